// Round 2
// baseline (299.142 us; speedup 1.0000x reference)
//
#include <hip/hip_runtime.h>
#include <math.h>

#define BS  2048
#define SEQ 200
#define DIM 64
#define C1  32
#define C2  16

__device__ __forceinline__ float dice1(float x, float m, float r, float al) {
    float t = (x - m) * r;
    float p = 1.f / (1.f + __expf(-t));
    return x * (al + p * (1.f - al));
}

// Fold W1 (256x32) into Wq = W1a+W1c, Wu = W1b-W1c, Wp = W1d  (each 64x32)
__global__ __launch_bounds__(256) void k_fold(const float* __restrict__ W1,
                                              float* __restrict__ Wq,
                                              float* __restrict__ Wu,
                                              float* __restrict__ Wp) {
    int i = blockIdx.x * 256 + threadIdx.x;
    if (i < DIM * C1) {
        float a = W1[i];
        float b = W1[DIM * C1 + i];
        float c = W1[2 * DIM * C1 + i];
        float d = W1[3 * DIM * C1 + i];
        Wq[i] = a + c;
        Wu[i] = b - c;
        Wp[i] = d;
    }
}

// One block per bs row: z1[bs][seq][c] = qW[c] + sum_d ub[seq][d] * (Wu[d][c] + q[d]*Wp[d][c])
__global__ __launch_bounds__(256) void k_gemm1(const float* __restrict__ q,
                                               const float* __restrict__ ub,
                                               const float* __restrict__ Wq,
                                               const float* __restrict__ Wu,
                                               const float* __restrict__ Wp,
                                               const float* __restrict__ b1,
                                               float* __restrict__ z1) {
    const int bs = blockIdx.x;
    const int tid = threadIdx.x;
    __shared__ float s_q[DIM];
    __shared__ __align__(16) float s_qw[C1];
    __shared__ __align__(16) float s_wc[DIM * C1];   // [64][32]
    __shared__ float s_ub[32 * 65];                  // 32 seq rows, pad 65

    if (tid < DIM) s_q[tid] = q[bs * DIM + tid];
    __syncthreads();
    for (int i = tid; i < DIM * C1; i += 256)
        s_wc[i] = Wu[i] + s_q[i >> 5] * Wp[i];
    if (tid < C1) {
        float a = b1[tid];
        #pragma unroll
        for (int d = 0; d < DIM; ++d) a = fmaf(s_q[d], Wq[(d << 5) + tid], a);
        s_qw[tid] = a;
    }

    const float4* wc4 = (const float4*)s_wc;
    const int sl = tid >> 3;   // 0..31 seq slot within chunk
    const int cq = tid & 7;    // 0..7 column quad
    const float* ub_b = ub + (size_t)bs * SEQ * DIM;
    float* z1_b = z1 + (size_t)bs * SEQ * C1;

    for (int s0 = 0; s0 < SEQ; s0 += 32) {
        const int cn = min(32, SEQ - s0);
        const float4* src = (const float4*)(ub_b + s0 * DIM);
        const int nf4 = cn * 16;
        __syncthreads();
        for (int i = tid; i < nf4; i += 256) {
            float4 v = src[i];
            int f = i * 4;
            int r = f >> 6, d = f & 63;
            float* dst = &s_ub[r * 65 + d];
            dst[0] = v.x; dst[1] = v.y; dst[2] = v.z; dst[3] = v.w;
        }
        __syncthreads();
        if (sl < cn) {
            float4 acc;
            acc.x = s_qw[cq * 4 + 0];
            acc.y = s_qw[cq * 4 + 1];
            acc.z = s_qw[cq * 4 + 2];
            acc.w = s_qw[cq * 4 + 3];
            const float* urow = &s_ub[sl * 65];
            #pragma unroll 16
            for (int d = 0; d < DIM; ++d) {
                float u = urow[d];
                float4 w = wc4[(d << 3) + cq];
                acc.x = fmaf(u, w.x, acc.x);
                acc.y = fmaf(u, w.y, acc.y);
                acc.z = fmaf(u, w.z, acc.z);
                acc.w = fmaf(u, w.w, acc.w);
            }
            ((float4*)(z1_b + (s0 + sl) * C1))[cq] = acc;
        }
    }
}

// One block per seq position: mean/rstd over the 2048 batch rows, per channel.
template <int C>
__global__ __launch_bounds__(1024) void k_red(const float* __restrict__ z,
                                              float* __restrict__ mu,
                                              float* __restrict__ rstd) {
    const int seq = blockIdx.x;
    const int tid = threadIdx.x;
    const int c = tid % C;
    const int g = tid / C;
    const int NG = 1024 / C;
    float s = 0.f, ss = 0.f;
    for (int b = g; b < BS; b += NG) {
        float v = z[((size_t)b * SEQ + seq) * C + c];
        s += v;
        ss = fmaf(v, v, ss);
    }
    __shared__ float sh_s[1024], sh_ss[1024];
    sh_s[tid] = s;
    sh_ss[tid] = ss;
    __syncthreads();
    if (tid < C) {
        float ts = 0.f, tss = 0.f;
        for (int g2 = 0; g2 < NG; ++g2) {
            ts += sh_s[g2 * C + c];
            tss += sh_ss[g2 * C + c];
        }
        float m = ts / (float)BS;
        float var = (tss - ts * m) / (float)(BS - 1);
        mu[seq * C + c] = m;
        rstd[seq * C + c] = rsqrtf(var + 1e-9f);
    }
}

// One block per bs: h1 = dice(z1), z2 = h1 @ W2 + b2
__global__ __launch_bounds__(256) void k_gemm2(const float* __restrict__ z1,
                                               const float* __restrict__ mu1,
                                               const float* __restrict__ rstd1,
                                               const float* __restrict__ alpha1,
                                               const float* __restrict__ W2,
                                               const float* __restrict__ b2,
                                               float* __restrict__ z2) {
    const int bs = blockIdx.x;
    const int tid = threadIdx.x;
    __shared__ __align__(16) float s_w2[C1 * C2];
    __shared__ float s_b2[C2];
    for (int i = tid; i < C1 * C2; i += 256) s_w2[i] = W2[i];
    if (tid < C2) s_b2[tid] = b2[tid];
    __syncthreads();
    if (tid >= SEQ) return;
    const float al = alpha1[0];
    const int seq = tid;
    const float4* z4 = (const float4*)(z1 + ((size_t)bs * SEQ + seq) * C1);
    const float4* m4 = (const float4*)(mu1 + seq * C1);
    const float4* r4 = (const float4*)(rstd1 + seq * C1);
    float h[C1];
    #pragma unroll
    for (int k = 0; k < C1 / 4; ++k) {
        float4 x = z4[k], m = m4[k], r = r4[k];
        h[k * 4 + 0] = dice1(x.x, m.x, r.x, al);
        h[k * 4 + 1] = dice1(x.y, m.y, r.y, al);
        h[k * 4 + 2] = dice1(x.z, m.z, r.z, al);
        h[k * 4 + 3] = dice1(x.w, m.w, r.w, al);
    }
    const float4* w4 = (const float4*)s_w2;  // [32 rows][4 quads]
    float4 o[4];
    #pragma unroll
    for (int qd = 0; qd < 4; ++qd) {
        o[qd].x = s_b2[qd * 4 + 0];
        o[qd].y = s_b2[qd * 4 + 1];
        o[qd].z = s_b2[qd * 4 + 2];
        o[qd].w = s_b2[qd * 4 + 3];
    }
    #pragma unroll
    for (int c = 0; c < C1; ++c) {
        float hc = h[c];
        #pragma unroll
        for (int qd = 0; qd < 4; ++qd) {
            float4 w = w4[c * 4 + qd];
            o[qd].x = fmaf(hc, w.x, o[qd].x);
            o[qd].y = fmaf(hc, w.y, o[qd].y);
            o[qd].z = fmaf(hc, w.z, o[qd].z);
            o[qd].w = fmaf(hc, w.w, o[qd].w);
        }
    }
    float4* outp = (float4*)(z2 + ((size_t)bs * SEQ + seq) * C2);
    #pragma unroll
    for (int qd = 0; qd < 4; ++qd) outp[qd] = o[qd];
}

// One block per bs: h2 = dice(z2), attn = (h2@W3+b3)*mask -> attns out,
// then output[bs][d] = sum_s ub[bs][s][d] * attn[s]
__global__ __launch_bounds__(256) void k_final(const float* __restrict__ z2,
                                               const float* __restrict__ mu2,
                                               const float* __restrict__ rstd2,
                                               const float* __restrict__ alpha2,
                                               const float* __restrict__ W3,
                                               const float* __restrict__ b3,
                                               const float* __restrict__ mask,
                                               const float* __restrict__ ub,
                                               float* __restrict__ out,
                                               float* __restrict__ attns) {
    const int bs = blockIdx.x;
    const int tid = threadIdx.x;
    __shared__ float s_attn[SEQ];
    __shared__ float s_w3[C2];
    __shared__ float s_part[4][DIM];
    if (tid < C2) s_w3[tid] = W3[tid];
    __syncthreads();
    if (tid < SEQ) {
        const float al = alpha2[0];
        const float bb3 = b3[0];
        const int seq = tid;
        const float4* z4 = (const float4*)(z2 + ((size_t)bs * SEQ + seq) * C2);
        const float4* m4 = (const float4*)(mu2 + seq * C2);
        const float4* r4 = (const float4*)(rstd2 + seq * C2);
        float a = bb3;
        #pragma unroll
        for (int k = 0; k < C2 / 4; ++k) {
            float4 x = z4[k], m = m4[k], r = r4[k];
            a = fmaf(dice1(x.x, m.x, r.x, al), s_w3[k * 4 + 0], a);
            a = fmaf(dice1(x.y, m.y, r.y, al), s_w3[k * 4 + 1], a);
            a = fmaf(dice1(x.z, m.z, r.z, al), s_w3[k * 4 + 2], a);
            a = fmaf(dice1(x.w, m.w, r.w, al), s_w3[k * 4 + 3], a);
        }
        a *= mask[bs * SEQ + seq];
        s_attn[seq] = a;
        attns[(size_t)bs * SEQ + seq] = a;
    }
    __syncthreads();
    const int d = tid & 63;
    const int sg = tid >> 6;
    float acc = 0.f;
    const float* ub_b = ub + (size_t)bs * SEQ * DIM;
    for (int s = sg; s < SEQ; s += 4)
        acc = fmaf(ub_b[s * DIM + d], s_attn[s], acc);
    s_part[sg][d] = acc;
    __syncthreads();
    if (tid < DIM) {
        float r = s_part[0][tid] + s_part[1][tid] + s_part[2][tid] + s_part[3][tid];
        out[(size_t)bs * DIM + tid] = r;
    }
}

extern "C" void kernel_launch(void* const* d_in, const int* in_sizes, int n_in,
                              void* d_out, int out_size, void* d_ws, size_t ws_size,
                              hipStream_t stream) {
    const float* q    = (const float*)d_in[0];
    const float* ub   = (const float*)d_in[1];
    const float* mask = (const float*)d_in[2];
    const float* W1   = (const float*)d_in[3];
    const float* b1   = (const float*)d_in[4];
    const float* a1   = (const float*)d_in[5];
    const float* W2   = (const float*)d_in[6];
    const float* b2   = (const float*)d_in[7];
    const float* a2   = (const float*)d_in[8];
    const float* W3   = (const float*)d_in[9];
    const float* b3   = (const float*)d_in[10];

    float* out   = (float*)d_out;            // (2048, 64)
    float* attns = out + (size_t)BS * DIM;   // (2048, 200)

    float* ws = (float*)d_ws;
    float* Wq = ws;                 // 2048
    float* Wu = Wq + 2048;          // 2048
    float* Wp = Wu + 2048;          // 2048
    float* z1 = Wp + 2048;          // BS*SEQ*C1 = 13107200
    float* z2 = z1 + (size_t)BS * SEQ * C1;   // 6553600
    float* mu1   = z2 + (size_t)BS * SEQ * C2;
    float* rstd1 = mu1 + SEQ * C1;
    float* mu2   = rstd1 + SEQ * C1;
    float* rstd2 = mu2 + SEQ * C2;

    hipLaunchKernelGGL(k_fold, dim3(8), dim3(256), 0, stream, W1, Wq, Wu, Wp);
    hipLaunchKernelGGL(k_gemm1, dim3(BS), dim3(256), 0, stream, q, ub, Wq, Wu, Wp, b1, z1);
    hipLaunchKernelGGL((k_red<C1>), dim3(SEQ), dim3(1024), 0, stream, z1, mu1, rstd1);
    hipLaunchKernelGGL(k_gemm2, dim3(BS), dim3(256), 0, stream, z1, mu1, rstd1, a1, W2, b2, z2);
    hipLaunchKernelGGL((k_red<C2>), dim3(SEQ), dim3(1024), 0, stream, z2, mu2, rstd2);
    hipLaunchKernelGGL(k_final, dim3(BS), dim3(256), 0, stream, z2, mu2, rstd2, a2, W3, b3, mask, ub, out, attns);
}

// Round 4
// 297.119 us; speedup vs baseline: 1.0068x; 1.0068x over previous
//
#include <hip/hip_runtime.h>
#include <math.h>

#define BS  2048
#define SEQ 200
#define DIM 64
#define C1  32
#define C2  16
#define PAD 68   // floats per staged ub row (17 float4; 68%32==4 -> 8 rows hit 8 banks)

__device__ __forceinline__ float dice1(float x, float m, float r, float al) {
    float t = (x - m) * r;
    float p = 1.f / (1.f + __expf(-t));
    return x * (al + p * (1.f - al));
}

// One block per bs row. Stage the whole 200x64 ub panel in LDS; each thread
// computes 7 seq rows x 4 channels so the d-loop is VALU-bound, not LDS-bound.
// W1 fold (Wq=W1a+W1c, Wu=W1b-W1c, Wp=W1d) is done inline from L2-hot W1.
__global__ __launch_bounds__(256) void k_gemm1(const float* __restrict__ q,
                                               const float* __restrict__ ub,
                                               const float* __restrict__ W1,
                                               const float* __restrict__ b1,
                                               float* __restrict__ z1) {
    const int bs = blockIdx.x;
    const int tid = threadIdx.x;
    __shared__ __align__(16) float s_ub[SEQ * PAD];   // 54.4 KB
    __shared__ __align__(16) float s_wc[DIM * C1];    // 8 KB  [64][32]
    __shared__ __align__(16) float s_qw[C1];

    float4* s_ub4 = (float4*)s_ub;
    const float4* s_wc4 = (const float4*)s_wc;
    const float* qrow = q + bs * DIM;
    const float* ub_b = ub + (size_t)bs * SEQ * DIM;

    // stage ub panel (coalesced float4)
    const float4* src4 = (const float4*)ub_b;
    for (int t = tid; t < SEQ * 16; t += 256)
        s_ub4[(t >> 4) * 17 + (t & 15)] = src4[t];

    // combined weight Wc[d][c] = (W1b - W1c)[d][c] + q[d]*W1d[d][c]
    const float4* w1b4 = (const float4*)(W1 + DIM * C1);
    const float4* w1c4 = (const float4*)(W1 + 2 * DIM * C1);
    const float4* w1d4 = (const float4*)(W1 + 3 * DIM * C1);
    for (int i4 = tid; i4 < DIM * C1 / 4; i4 += 256) {
        int d = i4 >> 3;
        float qd = qrow[d];
        float4 bb = w1b4[i4], cc = w1c4[i4], dd = w1d4[i4];
        float4 r;
        r.x = bb.x - cc.x + qd * dd.x;
        r.y = bb.y - cc.y + qd * dd.y;
        r.z = bb.z - cc.z + qd * dd.z;
        r.w = bb.w - cc.w + qd * dd.w;
        ((float4*)s_wc)[i4] = r;
    }
    // qw[c] = b1[c] + sum_d q[d] * (W1a + W1c)[d][c]   (seq-invariant term)
    if (tid < C1) {
        float a = b1[tid];
        #pragma unroll 8
        for (int d = 0; d < DIM; ++d)
            a = fmaf(qrow[d], W1[(d << 5) + tid] + W1[2 * DIM * C1 + (d << 5) + tid], a);
        s_qw[tid] = a;
    }
    __syncthreads();

    const int sl = tid >> 3;   // 0..31 seq lane
    const int cq = tid & 7;    // 0..7 channel quad
    const float4 qw = ((const float4*)s_qw)[cq];
    const float* su[7];
    float4 acc[7];
    #pragma unroll
    for (int i = 0; i < 7; ++i) {
        int r = sl + 32 * i;
        if (r > SEQ - 1) r = SEQ - 1;   // clamp: garbage computed, store guarded
        su[i] = s_ub + r * PAD;
        acc[i] = qw;
    }
    #pragma unroll 4
    for (int d = 0; d < DIM; ++d) {
        float4 w = s_wc4[(d << 3) + cq];
        #pragma unroll
        for (int i = 0; i < 7; ++i) {
            float u = su[i][d];
            acc[i].x = fmaf(u, w.x, acc[i].x);
            acc[i].y = fmaf(u, w.y, acc[i].y);
            acc[i].z = fmaf(u, w.z, acc[i].z);
            acc[i].w = fmaf(u, w.w, acc[i].w);
        }
    }
    float* z1_b = z1 + (size_t)bs * SEQ * C1;
    #pragma unroll
    for (int i = 0; i < 7; ++i) {
        int s = sl + 32 * i;
        if (s < SEQ) ((float4*)(z1_b + s * C1))[cq] = acc[i];
    }
}

// One block per seq position: mean/rstd over 2048 batch rows, float4-vectorized.
template <int C>
__global__ __launch_bounds__(1024) void k_red(const float* __restrict__ z,
                                              float* __restrict__ mu,
                                              float* __restrict__ rstd) {
    constexpr int Q = C / 4;
    constexpr int NG = 1024 / Q;
    const int seq = blockIdx.x;
    const int cq = threadIdx.x % Q;
    const int g = threadIdx.x / Q;
    float4 s = {0.f, 0.f, 0.f, 0.f}, ss = {0.f, 0.f, 0.f, 0.f};
    for (int b = g; b < BS; b += NG) {
        float4 v = *(const float4*)(z + ((size_t)b * SEQ + seq) * C + cq * 4);
        s.x += v.x; s.y += v.y; s.z += v.z; s.w += v.w;
        ss.x = fmaf(v.x, v.x, ss.x);
        ss.y = fmaf(v.y, v.y, ss.y);
        ss.z = fmaf(v.z, v.z, ss.z);
        ss.w = fmaf(v.w, v.w, ss.w);
    }
    __shared__ __align__(16) float4 sh_s[1024];
    __shared__ __align__(16) float4 sh_ss[1024];
    sh_s[threadIdx.x] = s;
    sh_ss[threadIdx.x] = ss;
    for (int h = NG / 2; h > 0; h >>= 1) {
        __syncthreads();
        if (g < h) {
            int o = threadIdx.x + h * Q;
            float4 s2 = sh_s[o], ss2 = sh_ss[o];
            s.x += s2.x; s.y += s2.y; s.z += s2.z; s.w += s2.w;
            ss.x += ss2.x; ss.y += ss2.y; ss.z += ss2.z; ss.w += ss2.w;
            sh_s[threadIdx.x] = s;
            sh_ss[threadIdx.x] = ss;
        }
    }
    if (g == 0) {
        const float inv_n = 1.f / (float)BS;
        const float inv_n1 = 1.f / (float)(BS - 1);
        float4 m, r;
        m.x = s.x * inv_n; m.y = s.y * inv_n; m.z = s.z * inv_n; m.w = s.w * inv_n;
        r.x = rsqrtf((ss.x - s.x * m.x) * inv_n1 + 1e-9f);
        r.y = rsqrtf((ss.y - s.y * m.y) * inv_n1 + 1e-9f);
        r.z = rsqrtf((ss.z - s.z * m.z) * inv_n1 + 1e-9f);
        r.w = rsqrtf((ss.w - s.w * m.w) * inv_n1 + 1e-9f);
        *(float4*)(mu + seq * C + cq * 4) = m;
        *(float4*)(rstd + seq * C + cq * 4) = r;
    }
}

// One block per bs: h1 = dice(z1), z2 = h1 @ W2 + b2
__global__ __launch_bounds__(256) void k_gemm2(const float* __restrict__ z1,
                                               const float* __restrict__ mu1,
                                               const float* __restrict__ rstd1,
                                               const float* __restrict__ alpha1,
                                               const float* __restrict__ W2,
                                               const float* __restrict__ b2,
                                               float* __restrict__ z2) {
    const int bs = blockIdx.x;
    const int tid = threadIdx.x;
    __shared__ __align__(16) float s_w2[C1 * C2];
    __shared__ float s_b2[C2];
    for (int i = tid; i < C1 * C2; i += 256) s_w2[i] = W2[i];
    if (tid < C2) s_b2[tid] = b2[tid];
    __syncthreads();
    if (tid >= SEQ) return;
    const float al = alpha1[0];
    const int seq = tid;
    const float4* z4 = (const float4*)(z1 + ((size_t)bs * SEQ + seq) * C1);
    const float4* m4 = (const float4*)(mu1 + seq * C1);
    const float4* r4 = (const float4*)(rstd1 + seq * C1);
    float h[C1];
    #pragma unroll
    for (int k = 0; k < C1 / 4; ++k) {
        float4 x = z4[k], m = m4[k], r = r4[k];
        h[k * 4 + 0] = dice1(x.x, m.x, r.x, al);
        h[k * 4 + 1] = dice1(x.y, m.y, r.y, al);
        h[k * 4 + 2] = dice1(x.z, m.z, r.z, al);
        h[k * 4 + 3] = dice1(x.w, m.w, r.w, al);
    }
    const float4* w4 = (const float4*)s_w2;
    float4 o[4];
    #pragma unroll
    for (int qd = 0; qd < 4; ++qd) {
        o[qd].x = s_b2[qd * 4 + 0];
        o[qd].y = s_b2[qd * 4 + 1];
        o[qd].z = s_b2[qd * 4 + 2];
        o[qd].w = s_b2[qd * 4 + 3];
    }
    #pragma unroll
    for (int c = 0; c < C1; ++c) {
        float hc = h[c];
        #pragma unroll
        for (int qd = 0; qd < 4; ++qd) {
            float4 w = w4[c * 4 + qd];
            o[qd].x = fmaf(hc, w.x, o[qd].x);
            o[qd].y = fmaf(hc, w.y, o[qd].y);
            o[qd].z = fmaf(hc, w.z, o[qd].z);
            o[qd].w = fmaf(hc, w.w, o[qd].w);
        }
    }
    float4* outp = (float4*)(z2 + ((size_t)bs * SEQ + seq) * C2);
    #pragma unroll
    for (int qd = 0; qd < 4; ++qd) outp[qd] = o[qd];
}

// One block per bs: h2 = dice(z2), attn = (h2@W3+b3)*mask, pooling over seq.
__global__ __launch_bounds__(256) void k_final(const float* __restrict__ z2,
                                               const float* __restrict__ mu2,
                                               const float* __restrict__ rstd2,
                                               const float* __restrict__ alpha2,
                                               const float* __restrict__ W3,
                                               const float* __restrict__ b3,
                                               const float* __restrict__ mask,
                                               const float* __restrict__ ub,
                                               float* __restrict__ out,
                                               float* __restrict__ attns) {
    const int bs = blockIdx.x;
    const int tid = threadIdx.x;
    __shared__ float s_attn[SEQ];
    __shared__ float s_w3[C2];
    __shared__ float s_part[4][DIM];
    if (tid < C2) s_w3[tid] = W3[tid];
    __syncthreads();
    if (tid < SEQ) {
        const float al = alpha2[0];
        const float bb3 = b3[0];
        const int seq = tid;
        const float4* z4 = (const float4*)(z2 + ((size_t)bs * SEQ + seq) * C2);
        const float4* m4 = (const float4*)(mu2 + seq * C2);
        const float4* r4 = (const float4*)(rstd2 + seq * C2);
        float a = bb3;
        #pragma unroll
        for (int k = 0; k < C2 / 4; ++k) {
            float4 x = z4[k], m = m4[k], r = r4[k];
            a = fmaf(dice1(x.x, m.x, r.x, al), s_w3[k * 4 + 0], a);
            a = fmaf(dice1(x.y, m.y, r.y, al), s_w3[k * 4 + 1], a);
            a = fmaf(dice1(x.z, m.z, r.z, al), s_w3[k * 4 + 2], a);
            a = fmaf(dice1(x.w, m.w, r.w, al), s_w3[k * 4 + 3], a);
        }
        a *= mask[bs * SEQ + seq];
        s_attn[seq] = a;
        attns[(size_t)bs * SEQ + seq] = a;
    }
    __syncthreads();
    const int d = tid & 63;
    const int sg = tid >> 6;
    float acc = 0.f;
    const float* ub_b = ub + (size_t)bs * SEQ * DIM;
    for (int s = sg; s < SEQ; s += 4)
        acc = fmaf(ub_b[s * DIM + d], s_attn[s], acc);
    s_part[sg][d] = acc;
    __syncthreads();
    if (tid < DIM) {
        float r = s_part[0][tid] + s_part[1][tid] + s_part[2][tid] + s_part[3][tid];
        out[(size_t)bs * DIM + tid] = r;
    }
}

extern "C" void kernel_launch(void* const* d_in, const int* in_sizes, int n_in,
                              void* d_out, int out_size, void* d_ws, size_t ws_size,
                              hipStream_t stream) {
    const float* q    = (const float*)d_in[0];
    const float* ub   = (const float*)d_in[1];
    const float* mask = (const float*)d_in[2];
    const float* W1   = (const float*)d_in[3];
    const float* b1   = (const float*)d_in[4];
    const float* a1   = (const float*)d_in[5];
    const float* W2   = (const float*)d_in[6];
    const float* b2   = (const float*)d_in[7];
    const float* a2   = (const float*)d_in[8];
    const float* W3   = (const float*)d_in[9];
    const float* b3   = (const float*)d_in[10];

    float* out   = (float*)d_out;            // (2048, 64)
    float* attns = out + (size_t)BS * DIM;   // (2048, 200, 1)

    float* ws = (float*)d_ws;
    float* z1 = ws;                                   // BS*SEQ*C1 = 13107200
    float* z2 = z1 + (size_t)BS * SEQ * C1;           // BS*SEQ*C2 = 6553600
    float* mu1   = z2 + (size_t)BS * SEQ * C2;
    float* rstd1 = mu1 + SEQ * C1;
    float* mu2   = rstd1 + SEQ * C1;
    float* rstd2 = mu2 + SEQ * C2;

    hipLaunchKernelGGL(k_gemm1, dim3(BS), dim3(256), 0, stream, q, ub, W1, b1, z1);
    hipLaunchKernelGGL((k_red<C1>), dim3(SEQ), dim3(1024), 0, stream, z1, mu1, rstd1);
    hipLaunchKernelGGL(k_gemm2, dim3(BS), dim3(256), 0, stream, z1, mu1, rstd1, a1, W2, b2, z2);
    hipLaunchKernelGGL((k_red<C2>), dim3(SEQ), dim3(1024), 0, stream, z2, mu2, rstd2);
    hipLaunchKernelGGL(k_final, dim3(BS), dim3(256), 0, stream, z2, mu2, rstd2, a2, W3, b3, mask, ub, out, attns);
}

// Round 7
// 272.746 us; speedup vs baseline: 1.0968x; 1.0894x over previous
//
#include <hip/hip_runtime.h>
#include <math.h>

#define BS  2048
#define SEQ 200
#define DIM 64
#define C1  32
#define C2  16

typedef __attribute__((ext_vector_type(8))) short bf16x8_t;
typedef __attribute__((ext_vector_type(4))) float f32x4_t;
typedef __attribute__((ext_vector_type(4))) short short4_t;

__device__ __forceinline__ float dice1(float x, float m, float r, float al) {
    float t = (x - m) * r;
    float p = 1.f / (1.f + __expf(-t));
    return x * (al + p * (1.f - al));
}

__device__ __forceinline__ unsigned short f2bf(float f) {
    union { float f; unsigned u; } a;
    a.f = f;
    unsigned r = a.u + 0x7fff + ((a.u >> 16) & 1);   // RNE
    return (unsigned short)(r >> 16);
}

// ---------------------------------------------------------------------------
// gemm1 via bf16 MFMA. One block per bs row.
// z1[s][c] = qw[c] + sum_d ub[s][d] * Wc[d][c],  Wc = W1b - W1c + q[d]*W1d.
// A panel: 208x64 bf16 in LDS, XOR-swizzled (byte ^= (row&7)<<4) so the
// 16-row A-fragment ds_read_b128 is conflict-free. B frags pre-arranged.
// ---------------------------------------------------------------------------
__global__ __launch_bounds__(256) void k_gemm1(const float* __restrict__ q,
                                               const float* __restrict__ ub,
                                               const float* __restrict__ W1,
                                               const float* __restrict__ b1,
                                               float* __restrict__ z1) {
    const int bs = blockIdx.x;
    const int tid = threadIdx.x;
    __shared__ __align__(16) short s_A[208 * 64];            // 26624 B, swizzled
    __shared__ __align__(16) short s_B[2 * 2 * 64 * 8];      // 4096 B, frag order
    __shared__ __align__(16) float s_qw[C1];

    char* sAc = (char*)s_A;
    const float* qrow = q + bs * DIM;
    const float4* src4 = (const float4*)(ub + (size_t)bs * SEQ * DIM);  // 3200 f4

    // ---- issue all 13 panel loads up-front (deep MLP), rows >=200 zeroed ----
    float4 st[13];
    #pragma unroll
    for (int it = 0; it < 13; ++it) {
        int i = tid + it * 256;                 // < 3328
        if (it < 12 || i < SEQ * 16) st[it] = src4[i];
        else { st[it].x = 0.f; st[it].y = 0.f; st[it].z = 0.f; st[it].w = 0.f; }
    }

    // ---- B fragments: thread t -> (kt,nt,lane), 8 k-elements each ----
    {
        const int kt = tid >> 7;
        const int nt = (tid >> 6) & 1;
        const int l  = tid & 63;
        const int c  = nt * 16 + (l & 15);
        bf16x8_t bfr;
        #pragma unroll
        for (int j = 0; j < 8; ++j) {
            int k = kt * 32 + ((l >> 4) << 3) + j;
            float wb = W1[(64 + k) * C1 + c] - W1[(128 + k) * C1 + c]
                     + qrow[k] * W1[(192 + k) * C1 + c];
            bfr[j] = (short)f2bf(wb);
        }
        *(bf16x8_t*)((char*)s_B + (((kt * 2 + nt) * 64) + l) * 16) = bfr;
    }
    // ---- seq-invariant term qw[c] = b1[c] + q . (W1a + W1c)[:,c] ----
    if (tid < C1) {
        float a = b1[tid];
        #pragma unroll 8
        for (int d = 0; d < DIM; ++d)
            a = fmaf(qrow[d], W1[d * C1 + tid] + W1[(128 + d) * C1 + tid], a);
        s_qw[tid] = a;
    }

    // ---- convert + swizzled store of the A panel (bf16) ----
    #pragma unroll
    for (int it = 0; it < 13; ++it) {
        int i = tid + it * 256;
        int row = i >> 4, f4 = i & 15;
        int off = row * 128 + ((f4 * 8) ^ ((row & 7) << 4));
        short4_t u;
        u.x = (short)f2bf(st[it].x);
        u.y = (short)f2bf(st[it].y);
        u.z = (short)f2bf(st[it].z);
        u.w = (short)f2bf(st[it].w);
        *(short4_t*)(sAc + off) = u;
    }
    __syncthreads();

    // ---- MFMA: wave w handles M-tiles w, w+4, w+8, w+12 ----
    const int wave = tid >> 6;
    const int l = tid & 63;
    const int g = l >> 4;            // k-group
    const bf16x8_t b00 = *(const bf16x8_t*)((char*)s_B + (0 * 64 + l) * 16); // kt0 nt0
    const bf16x8_t b01 = *(const bf16x8_t*)((char*)s_B + (1 * 64 + l) * 16); // kt0 nt1
    const bf16x8_t b10 = *(const bf16x8_t*)((char*)s_B + (2 * 64 + l) * 16); // kt1 nt0
    const bf16x8_t b11 = *(const bf16x8_t*)((char*)s_B + (3 * 64 + l) * 16); // kt1 nt1
    const float qw0 = s_qw[l & 15];
    const float qw1 = s_qw[16 + (l & 15)];
    float* z1_b = z1 + (size_t)bs * SEQ * C1;

    for (int mt = wave; mt < 13; mt += 4) {
        const int row = mt * 16 + (l & 15);
        const int sw = (row & 7) << 4;
        bf16x8_t a0 = *(const bf16x8_t*)(sAc + row * 128 + ((g * 16) ^ sw));
        bf16x8_t a1 = *(const bf16x8_t*)(sAc + row * 128 + (((64 + g * 16)) ^ sw));
        f32x4_t acc0 = {0.f, 0.f, 0.f, 0.f};
        f32x4_t acc1 = {0.f, 0.f, 0.f, 0.f};
        acc0 = __builtin_amdgcn_mfma_f32_16x16x32_bf16(a0, b00, acc0, 0, 0, 0);
        acc0 = __builtin_amdgcn_mfma_f32_16x16x32_bf16(a1, b10, acc0, 0, 0, 0);
        acc1 = __builtin_amdgcn_mfma_f32_16x16x32_bf16(a0, b01, acc1, 0, 0, 0);
        acc1 = __builtin_amdgcn_mfma_f32_16x16x32_bf16(a1, b11, acc1, 0, 0, 0);
        const int orow = mt * 16 + g * 4;
        #pragma unroll
        for (int r = 0; r < 4; ++r) {
            int rr = orow + r;
            if (rr < SEQ) {
                z1_b[rr * C1 + (l & 15)]      = acc0[r] + qw0;
                z1_b[rr * C1 + 16 + (l & 15)] = acc1[r] + qw1;
            }
        }
    }
}

// ---------------------------------------------------------------------------
// Stats stage A: grid (SEQ, 8); each block reduces 256 batch rows -> partials.
// ---------------------------------------------------------------------------
template <int C>
__global__ __launch_bounds__(256) void k_redA(const float* __restrict__ z,
                                              float* __restrict__ pS,
                                              float* __restrict__ pQ) {
    constexpr int Q = C / 4;
    constexpr int NG = 256 / Q;
    const int seq = blockIdx.x;
    const int part = blockIdx.y;
    const int cq = threadIdx.x % Q;
    const int g = threadIdx.x / Q;
    float4 s = {0.f, 0.f, 0.f, 0.f}, ss = {0.f, 0.f, 0.f, 0.f};
    const int b0 = part * 256;
    for (int b = b0 + g; b < b0 + 256; b += NG) {
        float4 v = *(const float4*)(z + ((size_t)b * SEQ + seq) * C + cq * 4);
        s.x += v.x; s.y += v.y; s.z += v.z; s.w += v.w;
        ss.x = fmaf(v.x, v.x, ss.x);
        ss.y = fmaf(v.y, v.y, ss.y);
        ss.z = fmaf(v.z, v.z, ss.z);
        ss.w = fmaf(v.w, v.w, ss.w);
    }
    __shared__ __align__(16) float4 sh_s[256];
    __shared__ __align__(16) float4 sh_q[256];
    sh_s[threadIdx.x] = s;
    sh_q[threadIdx.x] = ss;
    for (int h = NG / 2; h > 0; h >>= 1) {
        __syncthreads();
        if (g < h) {
            int o = threadIdx.x + h * Q;
            float4 s2 = sh_s[o], q2 = sh_q[o];
            s.x += s2.x; s.y += s2.y; s.z += s2.z; s.w += s2.w;
            ss.x += q2.x; ss.y += q2.y; ss.z += q2.z; ss.w += q2.w;
            sh_s[threadIdx.x] = s;
            sh_q[threadIdx.x] = ss;
        }
    }
    if (g == 0) {
        *(float4*)(pS + ((size_t)part * SEQ + seq) * C + cq * 4) = s;
        *(float4*)(pQ + ((size_t)part * SEQ + seq) * C + cq * 4) = ss;
    }
}

// Stats stage B: combine 8 partials -> mu, rstd.
template <int C>
__global__ __launch_bounds__(64) void k_redB(const float* __restrict__ pS,
                                             const float* __restrict__ pQ,
                                             float* __restrict__ mu,
                                             float* __restrict__ rstd) {
    const int seq = blockIdx.x;
    const int c = threadIdx.x;
    if (c >= C) return;
    float s = 0.f, ss = 0.f;
    #pragma unroll
    for (int p = 0; p < 8; ++p) {
        s += pS[((size_t)p * SEQ + seq) * C + c];
        ss += pQ[((size_t)p * SEQ + seq) * C + c];
    }
    float m = s / (float)BS;
    float var = (ss - s * m) / (float)(BS - 1);
    mu[seq * C + c] = m;
    rstd[seq * C + c] = rsqrtf(var + 1e-9f);
}

// ---------------------------------------------------------------------------
// gemm2: flattened over BS*SEQ items; all 256 threads active, coalesced.
// ---------------------------------------------------------------------------
__global__ __launch_bounds__(256) void k_gemm2(const float* __restrict__ z1,
                                               const float* __restrict__ mu1,
                                               const float* __restrict__ rstd1,
                                               const float* __restrict__ alpha1,
                                               const float* __restrict__ W2,
                                               const float* __restrict__ b2,
                                               float* __restrict__ z2) {
    const int tid = threadIdx.x;
    __shared__ __align__(16) float s_w2[C1 * C2];
    __shared__ float s_b2[C2];
    for (int i = tid; i < C1 * C2; i += 256) s_w2[i] = W2[i];
    if (tid < C2) s_b2[tid] = b2[tid];
    __syncthreads();
    const int gidx = blockIdx.x * 256 + tid;      // < BS*SEQ exactly
    const int bsb = gidx / SEQ;
    const int seq = gidx - bsb * SEQ;
    const float al = alpha1[0];
    const float4* z4 = (const float4*)(z1 + (size_t)gidx * C1);
    const float4* m4 = (const float4*)(mu1 + seq * C1);
    const float4* r4 = (const float4*)(rstd1 + seq * C1);
    float h[C1];
    #pragma unroll
    for (int k = 0; k < C1 / 4; ++k) {
        float4 x = z4[k], m = m4[k], r = r4[k];
        h[k * 4 + 0] = dice1(x.x, m.x, r.x, al);
        h[k * 4 + 1] = dice1(x.y, m.y, r.y, al);
        h[k * 4 + 2] = dice1(x.z, m.z, r.z, al);
        h[k * 4 + 3] = dice1(x.w, m.w, r.w, al);
    }
    const float4* w4 = (const float4*)s_w2;
    float4 o[4];
    #pragma unroll
    for (int qd = 0; qd < 4; ++qd) {
        o[qd].x = s_b2[qd * 4 + 0];
        o[qd].y = s_b2[qd * 4 + 1];
        o[qd].z = s_b2[qd * 4 + 2];
        o[qd].w = s_b2[qd * 4 + 3];
    }
    #pragma unroll
    for (int c = 0; c < C1; ++c) {
        float hc = h[c];
        #pragma unroll
        for (int qd = 0; qd < 4; ++qd) {
            float4 w = w4[c * 4 + qd];
            o[qd].x = fmaf(hc, w.x, o[qd].x);
            o[qd].y = fmaf(hc, w.y, o[qd].y);
            o[qd].z = fmaf(hc, w.z, o[qd].z);
            o[qd].w = fmaf(hc, w.w, o[qd].w);
        }
    }
    float4* outp = (float4*)(z2 + (size_t)gidx * C2);
    #pragma unroll
    for (int qd = 0; qd < 4; ++qd) outp[qd] = o[qd];
}

// ---------------------------------------------------------------------------
// final: dice2 -> attn -> masked pooling (float4-vectorized over d).
// ---------------------------------------------------------------------------
__global__ __launch_bounds__(256) void k_final(const float* __restrict__ z2,
                                               const float* __restrict__ mu2,
                                               const float* __restrict__ rstd2,
                                               const float* __restrict__ alpha2,
                                               const float* __restrict__ W3,
                                               const float* __restrict__ b3,
                                               const float* __restrict__ mask,
                                               const float* __restrict__ ub,
                                               float* __restrict__ out,
                                               float* __restrict__ attns) {
    const int bs = blockIdx.x;
    const int tid = threadIdx.x;
    __shared__ float s_attn[SEQ];
    __shared__ float s_w3[C2];
    __shared__ __align__(16) float4 s_pool[256];
    if (tid < C2) s_w3[tid] = W3[tid];
    __syncthreads();
    if (tid < SEQ) {
        const float al = alpha2[0];
        const float bb3 = b3[0];
        const float4* z4 = (const float4*)(z2 + ((size_t)bs * SEQ + tid) * C2);
        const float4* m4 = (const float4*)(mu2 + tid * C2);
        const float4* r4 = (const float4*)(rstd2 + tid * C2);
        float a = bb3;
        #pragma unroll
        for (int k = 0; k < C2 / 4; ++k) {
            float4 x = z4[k], m = m4[k], r = r4[k];
            a = fmaf(dice1(x.x, m.x, r.x, al), s_w3[k * 4 + 0], a);
            a = fmaf(dice1(x.y, m.y, r.y, al), s_w3[k * 4 + 1], a);
            a = fmaf(dice1(x.z, m.z, r.z, al), s_w3[k * 4 + 2], a);
            a = fmaf(dice1(x.w, m.w, r.w, al), s_w3[k * 4 + 3], a);
        }
        a *= mask[bs * SEQ + tid];
        s_attn[tid] = a;
        attns[(size_t)bs * SEQ + tid] = a;
    }
    __syncthreads();
    const int dq = tid & 15;   // float4 column within the 64-d row
    const int sg = tid >> 4;   // 0..15 seq-groups
    float4 acc = {0.f, 0.f, 0.f, 0.f};
    const float4* ub4 = (const float4*)(ub + (size_t)bs * SEQ * DIM);
    for (int s = sg; s < SEQ; s += 16) {
        float a = s_attn[s];
        float4 v = ub4[s * 16 + dq];
        acc.x = fmaf(v.x, a, acc.x);
        acc.y = fmaf(v.y, a, acc.y);
        acc.z = fmaf(v.z, a, acc.z);
        acc.w = fmaf(v.w, a, acc.w);
    }
    s_pool[tid] = acc;
    for (int h = 8; h > 0; h >>= 1) {
        __syncthreads();
        if (sg < h) {
            float4 o = s_pool[tid + h * 16];
            acc.x += o.x; acc.y += o.y; acc.z += o.z; acc.w += o.w;
            s_pool[tid] = acc;
        }
    }
    if (sg == 0)
        *(float4*)(out + (size_t)bs * DIM + dq * 4) = acc;
}

extern "C" void kernel_launch(void* const* d_in, const int* in_sizes, int n_in,
                              void* d_out, int out_size, void* d_ws, size_t ws_size,
                              hipStream_t stream) {
    const float* q    = (const float*)d_in[0];
    const float* ub   = (const float*)d_in[1];
    const float* mask = (const float*)d_in[2];
    const float* W1   = (const float*)d_in[3];
    const float* b1   = (const float*)d_in[4];
    const float* a1   = (const float*)d_in[5];
    const float* W2   = (const float*)d_in[6];
    const float* b2   = (const float*)d_in[7];
    const float* a2   = (const float*)d_in[8];
    const float* W3   = (const float*)d_in[9];
    const float* b3   = (const float*)d_in[10];

    float* out   = (float*)d_out;            // (2048, 64)
    float* attns = out + (size_t)BS * DIM;   // (2048, 200, 1)

    // ws layout identical in size to the known-passing round-2/4 config
    // (78.72 MB). Stats partials live in the attns region of d_out, which
    // k_redB consumes immediately and k_final fully overwrites afterwards.
    float* ws = (float*)d_ws;
    float* z1 = ws;                                   // 13107200
    float* z2 = z1 + (size_t)BS * SEQ * C1;           // 6553600
    float* mu1   = z2 + (size_t)BS * SEQ * C2;        // 6400
    float* rstd1 = mu1 + SEQ * C1;                    // 6400
    float* mu2   = rstd1 + SEQ * C1;                  // 3200
    float* rstd2 = mu2 + SEQ * C2;                    // 3200
    float* pS    = attns;                             // 8*SEQ*C1 = 51200 (scratch in d_out)
    float* pQ    = pS + 8 * SEQ * C1;                 // 51200 (total 102400 < 409600)

    hipLaunchKernelGGL(k_gemm1, dim3(BS), dim3(256), 0, stream, q, ub, W1, b1, z1);
    hipLaunchKernelGGL((k_redA<C1>), dim3(SEQ, 8), dim3(256), 0, stream, z1, pS, pQ);
    hipLaunchKernelGGL((k_redB<C1>), dim3(SEQ), dim3(64), 0, stream, pS, pQ, mu1, rstd1);
    hipLaunchKernelGGL(k_gemm2, dim3(BS * SEQ / 256), dim3(256), 0, stream, z1, mu1, rstd1, a1, W2, b2, z2);
    hipLaunchKernelGGL((k_redA<C2>), dim3(SEQ, 8), dim3(256), 0, stream, z2, pS, pQ);
    hipLaunchKernelGGL((k_redB<C2>), dim3(SEQ), dim3(64), 0, stream, pS, pQ, mu2, rstd2);
    hipLaunchKernelGGL(k_final, dim3(BS), dim3(256), 0, stream, z2, mu2, rstd2, a2, W3, b3, mask, ub, out, attns);
}

// Round 11
// 249.779 us; speedup vs baseline: 1.1976x; 1.0919x over previous
//
#include <hip/hip_runtime.h>
#include <math.h>

#define BS  2048
#define SEQ 200
#define DIM 64
#define C1  32
#define C2  16

typedef __attribute__((ext_vector_type(8))) short bf16x8_t;
typedef __attribute__((ext_vector_type(4))) float f32x4_t;

__device__ __forceinline__ float dice1(float x, float m, float r, float al) {
    float t = (x - m) * r;
    float p = 1.f / (1.f + __expf(-t));
    return x * (al + p * (1.f - al));
}

__device__ __forceinline__ unsigned short f2bf(float f) {
    union { float f; unsigned u; } a;
    a.f = f;
    unsigned r = a.u + 0x7fff + ((a.u >> 16) & 1);   // RNE
    return (unsigned short)(r >> 16);
}

__device__ __forceinline__ float bf2f(short h) {
    union { unsigned u; float f; } a;
    a.u = ((unsigned)(unsigned short)h) << 16;
    return a.f;
}

// ---------------------------------------------------------------------------
// k1: gemm1 via bf16 MFMA, A-fragments loaded DIRECTLY from global (no LDS
// staging, no staging barrier). One block per bs row. z1 out is bf16,
// repacked through LDS for coalesced 16B stores.
// z1[s][c] = qw[c] + sum_d ub[s][d]*Wc[d][c],  Wc = W1b - W1c + q[d]*W1d.
// ---------------------------------------------------------------------------
__global__ __launch_bounds__(256) void k_gemm1(const float* __restrict__ q,
                                               const float* __restrict__ ub,
                                               const float* __restrict__ W1,
                                               const float* __restrict__ b1,
                                               short* __restrict__ z1) {
    const int bs = blockIdx.x;
    const int tid = threadIdx.x;
    __shared__ __align__(16) short s_B[2 * 2 * 64 * 8];   // 4 KB, frag order
    __shared__ __align__(16) float s_qw[C1];
    __shared__ __align__(16) short s_z[208 * C1];         // 13.3 KB repack buf

    const float* qrow = q + bs * DIM;

    // ---- B fragments: thread t -> (kt,nt,lane), 8 k-elements each ----
    {
        const int kt = tid >> 7;
        const int nt = (tid >> 6) & 1;
        const int l  = tid & 63;
        const int c  = nt * 16 + (l & 15);
        bf16x8_t bfr;
        #pragma unroll
        for (int j = 0; j < 8; ++j) {
            int k = kt * 32 + ((l >> 4) << 3) + j;
            float wb = W1[(64 + k) * C1 + c] - W1[(128 + k) * C1 + c]
                     + qrow[k] * W1[(192 + k) * C1 + c];
            bfr[j] = (short)f2bf(wb);
        }
        *(bf16x8_t*)((char*)s_B + (((kt * 2 + nt) * 64) + l) * 16) = bfr;
    }
    // ---- qw[c] = b1[c] + q . (W1a + W1c)[:,c] ----
    if (tid < C1) {
        float a = b1[tid];
        #pragma unroll 8
        for (int d = 0; d < DIM; ++d)
            a = fmaf(qrow[d], W1[d * C1 + tid] + W1[(128 + d) * C1 + tid], a);
        s_qw[tid] = a;
    }
    __syncthreads();

    const int wave = tid >> 6;
    const int l = tid & 63;
    const int g = l >> 4;
    const bf16x8_t b00 = *(const bf16x8_t*)((char*)s_B + (0 * 64 + l) * 16);
    const bf16x8_t b01 = *(const bf16x8_t*)((char*)s_B + (1 * 64 + l) * 16);
    const bf16x8_t b10 = *(const bf16x8_t*)((char*)s_B + (2 * 64 + l) * 16);
    const bf16x8_t b11 = *(const bf16x8_t*)((char*)s_B + (3 * 64 + l) * 16);
    const float qw0 = s_qw[l & 15];
    const float qw1 = s_qw[16 + (l & 15)];
    const float* ubb = ub + (size_t)bs * SEQ * DIM;

    for (int mt = wave; mt < 13; mt += 4) {
        int row = mt * 16 + (l & 15);
        int rc = row > SEQ - 1 ? SEQ - 1 : row;   // clamp; garbage rows dropped
        const float* rp = ubb + rc * DIM + g * 8;
        float4 f0 = *(const float4*)(rp);
        float4 f1 = *(const float4*)(rp + 4);
        float4 f2 = *(const float4*)(rp + 32);
        float4 f3 = *(const float4*)(rp + 36);
        bf16x8_t a0, a1;
        a0[0] = (short)f2bf(f0.x); a0[1] = (short)f2bf(f0.y);
        a0[2] = (short)f2bf(f0.z); a0[3] = (short)f2bf(f0.w);
        a0[4] = (short)f2bf(f1.x); a0[5] = (short)f2bf(f1.y);
        a0[6] = (short)f2bf(f1.z); a0[7] = (short)f2bf(f1.w);
        a1[0] = (short)f2bf(f2.x); a1[1] = (short)f2bf(f2.y);
        a1[2] = (short)f2bf(f2.z); a1[3] = (short)f2bf(f2.w);
        a1[4] = (short)f2bf(f3.x); a1[5] = (short)f2bf(f3.y);
        a1[6] = (short)f2bf(f3.z); a1[7] = (short)f2bf(f3.w);
        f32x4_t acc0 = {0.f, 0.f, 0.f, 0.f};
        f32x4_t acc1 = {0.f, 0.f, 0.f, 0.f};
        acc0 = __builtin_amdgcn_mfma_f32_16x16x32_bf16(a0, b00, acc0, 0, 0, 0);
        acc0 = __builtin_amdgcn_mfma_f32_16x16x32_bf16(a1, b10, acc0, 0, 0, 0);
        acc1 = __builtin_amdgcn_mfma_f32_16x16x32_bf16(a0, b01, acc1, 0, 0, 0);
        acc1 = __builtin_amdgcn_mfma_f32_16x16x32_bf16(a1, b11, acc1, 0, 0, 0);
        const int orow = mt * 16 + g * 4;
        #pragma unroll
        for (int r = 0; r < 4; ++r) {
            s_z[(orow + r) * C1 + (l & 15)]      = (short)f2bf(acc0[r] + qw0);
            s_z[(orow + r) * C1 + 16 + (l & 15)] = (short)f2bf(acc1[r] + qw1);
        }
    }
    __syncthreads();
    // coalesced copy-out: 200*32 bf16 = 800 x 16B
    bf16x8_t* dst = (bf16x8_t*)(z1 + (size_t)bs * SEQ * C1);
    const bf16x8_t* srcl = (const bf16x8_t*)s_z;
    for (int i = tid; i < SEQ * C1 / 8; i += 256) dst[i] = srcl[i];
}

// ---------------------------------------------------------------------------
// k2: stats1 partials over bf16 z1. Grid (SEQ, 8 parts), 256 thr.
// Thread = (bs_sub = tid>>2, cq = tid&3) reading bf16x8; shfl-tree reduce.
// ---------------------------------------------------------------------------
__global__ __launch_bounds__(256) void k_redA1(const short* __restrict__ z1,
                                               float* __restrict__ pS,
                                               float* __restrict__ pQ) {
    const int seq = blockIdx.x;
    const int part = blockIdx.y;
    const int tid = threadIdx.x;
    const int cq = tid & 3;
    float s[8], qq[8];
    #pragma unroll
    for (int j = 0; j < 8; ++j) { s[j] = 0.f; qq[j] = 0.f; }
    #pragma unroll
    for (int it = 0; it < 4; ++it) {
        int b = part * 256 + (tid >> 2) + it * 64;
        bf16x8_t v = *(const bf16x8_t*)(z1 + ((size_t)b * SEQ + seq) * C1 + cq * 8);
        #pragma unroll
        for (int j = 0; j < 8; ++j) {
            float f = bf2f(v[j]);
            s[j] += f;
            qq[j] = fmaf(f, f, qq[j]);
        }
    }
    // intra-wave: reduce over the 16 bs_sub lanes sharing cq (strides 4..32)
    #pragma unroll
    for (int st = 4; st <= 32; st <<= 1) {
        #pragma unroll
        for (int j = 0; j < 8; ++j) {
            s[j]  += __shfl_xor(s[j],  st);
            qq[j] += __shfl_xor(qq[j], st);
        }
    }
    __shared__ float shS[4][4][8], shQ[4][4][8];
    const int wave = tid >> 6, l = tid & 63;
    if (l < 4) {
        #pragma unroll
        for (int j = 0; j < 8; ++j) { shS[wave][l][j] = s[j]; shQ[wave][l][j] = qq[j]; }
    }
    __syncthreads();
    if (tid < 32) {
        int c4 = tid >> 3, j = tid & 7;
        float a = shS[0][c4][j] + shS[1][c4][j] + shS[2][c4][j] + shS[3][c4][j];
        float b = shQ[0][c4][j] + shQ[1][c4][j] + shQ[2][c4][j] + shQ[3][c4][j];
        pS[((size_t)part * SEQ + seq) * C1 + c4 * 8 + j] = a;
        pQ[((size_t)part * SEQ + seq) * C1 + c4 * 8 + j] = b;
    }
}

// ---------------------------------------------------------------------------
// k3: fused dice1 + gemm2 (MFMA) + stats2 partials.
// Grid (25 seq-strips, 8 parts), 256 thr = 4 waves. Wave handles 2 seqs x
// 16 bs-tiles of 16 rows. mu1/rstd1 combined redundantly per block from
// L2-hot partials. A-frag redistribution via shfl (no barrier).
// ---------------------------------------------------------------------------
__global__ __launch_bounds__(256) void k_gemm2s(const short* __restrict__ z1,
                                                const float* __restrict__ pS1,
                                                const float* __restrict__ pQ1,
                                                const float* __restrict__ alpha1,
                                                const float* __restrict__ W2,
                                                const float* __restrict__ b2,
                                                short* __restrict__ z2,
                                                float* __restrict__ pS2,
                                                float* __restrict__ pQ2) {
    const int strip = blockIdx.x;   // 8 seqs
    const int part = blockIdx.y;    // 256 bs
    const int tid = threadIdx.x;
    __shared__ float s_mu[8][C1];
    __shared__ float s_rs[8][C1];

    // combine stats1 partials for this strip (256 cells = 8 seq x 32 ch)
    {
        int ss = tid >> 5, c = tid & 31;
        int seqg = strip * 8 + ss;
        float s = 0.f, q = 0.f;
        #pragma unroll
        for (int p = 0; p < 8; ++p) {
            s += pS1[((size_t)p * SEQ + seqg) * C1 + c];
            q += pQ1[((size_t)p * SEQ + seqg) * C1 + c];
        }
        float m = s / (float)BS;
        float var = (q - s * m) / (float)(BS - 1);
        s_mu[ss][c] = m;
        s_rs[ss][c] = rsqrtf(var + 1e-9f);
    }
    const int wave = tid >> 6;
    const int l = tid & 63;
    const int g = l >> 4;
    const int cB = l & 15;
    // B-frag: W2[k][c], k = g*8+j
    bf16x8_t bw;
    #pragma unroll
    for (int j = 0; j < 8; ++j) bw[j] = (short)f2bf(W2[(g * 8 + j) * C2 + cB]);
    const float bias = b2[cB];
    const float al = alpha1[0];
    __syncthreads();

    const int cb = (l & 3) * 8;      // producer channel base
    const int srcLane = (l & 15) * 4 + g;
    for (int sq = wave * 2; sq < wave * 2 + 2; ++sq) {
        const int seqg = strip * 8 + sq;
        float sumS = 0.f, sumQ = 0.f;
        for (int t = 0; t < 16; ++t) {
            const int b0 = part * 256 + t * 16;
            const int brow = b0 + (l >> 2);
            bf16x8_t zv = *(const bf16x8_t*)(z1 + ((size_t)brow * SEQ + seqg) * C1 + cb);
            // dice1 on 8 channels
            union { bf16x8_t v; int w[4]; } hp;
            #pragma unroll
            for (int j = 0; j < 8; ++j) {
                float x = bf2f(zv[j]);
                hp.v[j] = (short)f2bf(dice1(x, s_mu[sq][cb + j], s_rs[sq][cb + j], al));
            }
            // redistribute to A-frag layout via shfl
            union { bf16x8_t v; int w[4]; } af;
            #pragma unroll
            for (int w4 = 0; w4 < 4; ++w4) af.w[w4] = __shfl(hp.w[w4], srcLane);
            f32x4_t acc = {bias, bias, bias, bias};
            acc = __builtin_amdgcn_mfma_f32_16x16x32_bf16(af.v, bw, acc, 0, 0, 0);
            #pragma unroll
            for (int r = 0; r < 4; ++r) {
                int rb = b0 + g * 4 + r;
                z2[((size_t)rb * SEQ + seqg) * C2 + cB] = (short)f2bf(acc[r]);
                sumS += acc[r];
                sumQ = fmaf(acc[r], acc[r], sumQ);
            }
        }
        // reduce over the 4 g-groups sharing col cB
        sumS += __shfl_xor(sumS, 16); sumS += __shfl_xor(sumS, 32);
        sumQ += __shfl_xor(sumQ, 16); sumQ += __shfl_xor(sumQ, 32);
        if (l < 16) {
            pS2[((size_t)part * SEQ + seqg) * C2 + cB] = sumS;
            pQ2[((size_t)part * SEQ + seqg) * C2 + cB] = sumQ;
        }
    }
}

// k4: combine stats2 partials -> mu2, rstd2. 3200 cells.
__global__ __launch_bounds__(64) void k_redB2(const float* __restrict__ pS,
                                              const float* __restrict__ pQ,
                                              float* __restrict__ mu,
                                              float* __restrict__ rstd) {
    const int cell = blockIdx.x * 64 + threadIdx.x;   // < SEQ*C2 = 3200
    const int seq = cell >> 4, c = cell & 15;
    float s = 0.f, q = 0.f;
    #pragma unroll
    for (int p = 0; p < 8; ++p) {
        s += pS[((size_t)p * SEQ + seq) * C2 + c];
        q += pQ[((size_t)p * SEQ + seq) * C2 + c];
    }
    float m = s / (float)BS;
    float var = (q - s * m) / (float)(BS - 1);
    mu[seq * C2 + c] = m;
    rstd[seq * C2 + c] = rsqrtf(var + 1e-9f);
}

// ---------------------------------------------------------------------------
// k5: dice2 -> attn -> masked pooling. One block per bs.
// ---------------------------------------------------------------------------
__global__ __launch_bounds__(256) void k_final(const short* __restrict__ z2,
                                               const float* __restrict__ mu2,
                                               const float* __restrict__ rstd2,
                                               const float* __restrict__ alpha2,
                                               const float* __restrict__ W3,
                                               const float* __restrict__ b3,
                                               const float* __restrict__ mask,
                                               const float* __restrict__ ub,
                                               float* __restrict__ out,
                                               float* __restrict__ attns) {
    const int bs = blockIdx.x;
    const int tid = threadIdx.x;
    __shared__ float s_attn[SEQ];
    __shared__ float s_w3[C2];
    __shared__ __align__(16) float4 s_pool[256];
    if (tid < C2) s_w3[tid] = W3[tid];
    __syncthreads();
    if (tid < SEQ) {
        const float al = alpha2[0];
        const float bb3 = b3[0];
        bf16x8_t v0 = *(const bf16x8_t*)(z2 + ((size_t)bs * SEQ + tid) * C2);
        bf16x8_t v1 = *(const bf16x8_t*)(z2 + ((size_t)bs * SEQ + tid) * C2 + 8);
        const float4* m4 = (const float4*)(mu2 + tid * C2);
        const float4* r4 = (const float4*)(rstd2 + tid * C2);
        float a = bb3;
        #pragma unroll
        for (int k = 0; k < 4; ++k) {
            float4 m = m4[k], r = r4[k];
            float x0 = bf2f(k < 2 ? v0[k * 4 + 0] : v1[(k - 2) * 4 + 0]);
            float x1 = bf2f(k < 2 ? v0[k * 4 + 1] : v1[(k - 2) * 4 + 1]);
            float x2 = bf2f(k < 2 ? v0[k * 4 + 2] : v1[(k - 2) * 4 + 2]);
            float x3 = bf2f(k < 2 ? v0[k * 4 + 3] : v1[(k - 2) * 4 + 3]);
            a = fmaf(dice1(x0, m.x, r.x, al), s_w3[k * 4 + 0], a);
            a = fmaf(dice1(x1, m.y, r.y, al), s_w3[k * 4 + 1], a);
            a = fmaf(dice1(x2, m.z, r.z, al), s_w3[k * 4 + 2], a);
            a = fmaf(dice1(x3, m.w, r.w, al), s_w3[k * 4 + 3], a);
        }
        a *= mask[bs * SEQ + tid];
        s_attn[tid] = a;
        attns[(size_t)bs * SEQ + tid] = a;
    }
    __syncthreads();
    const int dq = tid & 15;
    const int sg = tid >> 4;
    float4 acc = {0.f, 0.f, 0.f, 0.f};
    const float4* ub4 = (const float4*)(ub + (size_t)bs * SEQ * DIM);
    for (int s = sg; s < SEQ; s += 16) {
        float a = s_attn[s];
        float4 v = ub4[s * 16 + dq];
        acc.x = fmaf(v.x, a, acc.x);
        acc.y = fmaf(v.y, a, acc.y);
        acc.z = fmaf(v.z, a, acc.z);
        acc.w = fmaf(v.w, a, acc.w);
    }
    s_pool[tid] = acc;
    for (int h = 8; h > 0; h >>= 1) {
        __syncthreads();
        if (sg < h) {
            float4 o = s_pool[tid + h * 16];
            acc.x += o.x; acc.y += o.y; acc.z += o.z; acc.w += o.w;
            s_pool[tid] = acc;
        }
    }
    if (sg == 0)
        *(float4*)(out + (size_t)bs * DIM + dq * 4) = acc;
}

extern "C" void kernel_launch(void* const* d_in, const int* in_sizes, int n_in,
                              void* d_out, int out_size, void* d_ws, size_t ws_size,
                              hipStream_t stream) {
    const float* q    = (const float*)d_in[0];
    const float* ub   = (const float*)d_in[1];
    const float* mask = (const float*)d_in[2];
    const float* W1   = (const float*)d_in[3];
    const float* b1   = (const float*)d_in[4];
    const float* a1   = (const float*)d_in[5];
    const float* W2   = (const float*)d_in[6];
    const float* b2   = (const float*)d_in[7];
    const float* a2   = (const float*)d_in[8];
    const float* W3   = (const float*)d_in[9];
    const float* b3   = (const float*)d_in[10];

    float* out   = (float*)d_out;            // (2048, 64)
    float* attns = out + (size_t)BS * DIM;   // (2048, 200, 1)

    float* ws = (float*)d_ws;
    short* z1 = (short*)ws;                              // BS*SEQ*C1 bf16 (26.2 MB)
    short* z2 = z1 + (size_t)BS * SEQ * C1;              // BS*SEQ*C2 bf16 (13.1 MB)
    float* fw = (float*)(z2 + (size_t)BS * SEQ * C2);
    float* pS1 = fw;                    // 8*SEQ*C1 = 51200
    float* pQ1 = pS1 + 8 * SEQ * C1;    // 51200
    float* pS2 = pQ1 + 8 * SEQ * C1;    // 8*SEQ*C2 = 25600
    float* pQ2 = pS2 + 8 * SEQ * C2;    // 25600
    float* mu2   = pQ2 + 8 * SEQ * C2;  // 3200
    float* rstd2 = mu2 + SEQ * C2;      // 3200

    hipLaunchKernelGGL(k_gemm1, dim3(BS), dim3(256), 0, stream, q, ub, W1, b1, z1);
    hipLaunchKernelGGL(k_redA1, dim3(SEQ, 8), dim3(256), 0, stream, z1, pS1, pQ1);
    hipLaunchKernelGGL(k_gemm2s, dim3(25, 8), dim3(256), 0, stream,
                       z1, pS1, pQ1, a1, W2, b2, z2, pS2, pQ2);
    hipLaunchKernelGGL(k_redB2, dim3(50), dim3(64), 0, stream, pS2, pQ2, mu2, rstd2);
    hipLaunchKernelGGL(k_final, dim3(BS), dim3(256), 0, stream,
                       z2, mu2, rstd2, a2, W3, b3, mask, ub, out, attns);
}